// Round 9
// baseline (1257.439 us; speedup 1.0000x reference)
//
#include <hip/hip_runtime.h>

#define B 8
#define S 1024
#define DM 512
#define H 8
#define D 64

typedef __attribute__((ext_vector_type(8))) short bf16x8;
typedef __attribute__((ext_vector_type(4))) float f32x4;

__device__ inline f32x4 mfma16(bf16x8 a, bf16x8 b, f32x4 c) {
  return __builtin_amdgcn_mfma_f32_16x16x32_bf16(a, b, c, 0, 0, 0);
}

__device__ inline ushort f2bf(float f) {
  uint u = __float_as_uint(f);
  u += 0x7fff + ((u >> 16) & 1);   // round-to-nearest-even
  return (ushort)(u >> 16);
}

__device__ inline float bf2f(ushort u) {
  return __uint_as_float(((uint)u) << 16);
}

// ---------------------------------------------------------------------------
// Cast x [B,S,DM] f32 -> bf16, vectorized.
// ---------------------------------------------------------------------------
__global__ __launch_bounds__(256) void cast_x_kernel(const float* __restrict__ x,
                                                     ushort* __restrict__ xbf) {
  int idx = blockIdx.x * 256 + threadIdx.x;         // one float4 per thread
  float4 v = *(const float4*)(x + (size_t)idx * 4);
  ushort4 o;
  o.x = f2bf(v.x); o.y = f2bf(v.y); o.z = f2bf(v.z); o.w = f2bf(v.w);
  *(ushort4*)(xbf + (size_t)idx * 4) = o;
}

// ---------------------------------------------------------------------------
// Weight prep: WT[f][m] = W{q,k,v}[h][m][d] (f = g*512 + h*64 + d), bf16.
//              WoT[m][f] = Wo[f][m], bf16.
// ---------------------------------------------------------------------------
__global__ __launch_bounds__(256) void prep_w_kernel(
    const float* __restrict__ Wq, const float* __restrict__ Wk,
    const float* __restrict__ Wv, const float* __restrict__ Wo,
    ushort* __restrict__ WT, ushort* __restrict__ WoT) {
  int idx = blockIdx.x * 256 + threadIdx.x;
  if (idx < 1536 * 512) {
    int f = idx >> 9, m = idx & 511;
    int g = f >> 9, fl = f & 511, h = fl >> 6, d = fl & 63;
    const float* W = (g == 0) ? Wq : (g == 1) ? Wk : Wv;
    WT[idx] = f2bf(W[((size_t)h * DM + m) * D + d]);
  } else {
    int i2 = idx - 1536 * 512;                      // [0, 512*512)
    int m = i2 >> 9, f = i2 & 511;
    WoT[(size_t)m * 512 + f] = f2bf(Wo[(size_t)f * DM + m]);
  }
}

// ---------------------------------------------------------------------------
// QKV GEMM: C[s][f] = sum_m xbf[s][m] * WT[f][m]   (M=8192, N=1536, K=512)
// 64x64 tile, 4 waves. Epilogue scatters to q/k [b,h,s,d] and vT [b,h,d,s].
// ---------------------------------------------------------------------------
__global__ __launch_bounds__(256) void qkv_gemm_kernel(
    const ushort* __restrict__ A, const ushort* __restrict__ Bm,
    ushort* __restrict__ qb, ushort* __restrict__ kb, ushort* __restrict__ vt) {
  __shared__ ushort As[64][72], Bs[64][72];         // +16B pad per row
  const int tid = threadIdx.x;
  const int m0 = blockIdx.x * 64, n0 = blockIdx.y * 64;
  const int w = tid >> 6, l = tid & 63;
  const int r = l & 15, q = l >> 4;
  const int mh = (w >> 1) * 32, nh = (w & 1) * 32;

  f32x4 acc[2][2] = {};
  const int srow = tid >> 2, sco = (tid & 3) * 16;  // staging: 32B per thread

  for (int k0 = 0; k0 < 512; k0 += 64) {
    const ushort* ap = A + (size_t)(m0 + srow) * 512 + k0 + sco;
    const ushort* bp = Bm + (size_t)(n0 + srow) * 512 + k0 + sco;
    uint4 a0 = *(const uint4*)ap;
    uint4 a1 = *(const uint4*)(ap + 8);
    uint4 b0 = *(const uint4*)bp;
    uint4 b1 = *(const uint4*)(bp + 8);
    __syncthreads();
    *(uint4*)&As[srow][sco] = a0;
    *(uint4*)&As[srow][sco + 8] = a1;
    *(uint4*)&Bs[srow][sco] = b0;
    *(uint4*)&Bs[srow][sco + 8] = b1;
    __syncthreads();
    #pragma unroll
    for (int kk = 0; kk < 64; kk += 32) {
      bf16x8 fa0 = *(const bf16x8*)&As[mh + r][kk + q * 8];
      bf16x8 fa1 = *(const bf16x8*)&As[mh + 16 + r][kk + q * 8];
      bf16x8 fb0 = *(const bf16x8*)&Bs[nh + r][kk + q * 8];
      bf16x8 fb1 = *(const bf16x8*)&Bs[nh + 16 + r][kk + q * 8];
      acc[0][0] = mfma16(fa0, fb0, acc[0][0]);
      acc[0][1] = mfma16(fa0, fb1, acc[0][1]);
      acc[1][0] = mfma16(fa1, fb0, acc[1][0]);
      acc[1][1] = mfma16(fa1, fb1, acc[1][1]);
    }
  }

  const int g = n0 >> 9;                            // 0=q 1=k 2=v, block-uniform
  #pragma unroll
  for (int mi = 0; mi < 2; ++mi)
    #pragma unroll
    for (int nj = 0; nj < 2; ++nj)
      #pragma unroll
      for (int i = 0; i < 4; ++i) {
        int row = m0 + mh + mi * 16 + q * 4 + i;    // global s-row
        int col = n0 + nh + nj * 16 + r;            // global f
        int bb = row >> 10, s = row & 1023;
        int fl = col & 511, h = fl >> 6, d = fl & 63;
        ushort val = f2bf(acc[mi][nj][i]);
        if (g == 0)
          qb[(((size_t)bb * H + h) * S + s) * D + d] = val;
        else if (g == 1)
          kb[(((size_t)bb * H + h) * S + s) * D + d] = val;
        else
          vt[(((size_t)bb * H + h) * D + d) * S + s] = val;
      }
}

// ---------------------------------------------------------------------------
// Attention body (shared by ablation variants). REP = idempotent repeats
// (opaque-zero offset defeats CSE/LICM); DO_STORE gates the attn global
// store (PV + concat keep all upstream live when off).
// ---------------------------------------------------------------------------
template <int REP, bool DO_STORE>
__device__ __forceinline__ void attn_body(
    const ushort* __restrict__ qb, const ushort* __restrict__ kb,
    const ushort* __restrict__ vt, float* __restrict__ attn,
    ushort* __restrict__ concat) {
  __shared__ ushort Pl[16 * 1024];                  // 32 KB, swizzled bf16 P
  __shared__ float redm[4][16], redsum[4][16];      // 512 B
  __shared__ float rinvL[16];                       // per-row 1/sum broadcast
  const int tid = threadIdx.x;
  const int w = tid >> 6, l = tid & 63;
  const int r = l & 15, q = l >> 4;

  // dispatch-scheme-robust locality mapping (see R8 notes)
  const int n = blockIdx.x;
  const int rank = n >> 3;
  const int bh = (n & 7) * 8 + (rank >> 6);
  const int s0 = (rank & 63) * 16;

  int zoff = 0;
  #pragma unroll 1
  for (int rep = 0; rep < REP; ++rep) {
    asm volatile("" : "+v"(zoff));                  // stays 0; blocks CSE/LICM

    const ushort* qp = qb + ((size_t)bh * S + s0) * D + zoff;
    bf16x8 qa0 = *(const bf16x8*)(qp + r * 64 + q * 8);
    bf16x8 qa1 = *(const bf16x8*)(qp + r * 64 + 32 + q * 8);

    const ushort* kp = kb + (size_t)bh * S * D + zoff;
    f32x4 sc[16];
    #pragma unroll
    for (int kt = 0; kt < 16; ++kt) {
      const ushort* kr = kp + (size_t)(w * 256 + kt * 16 + r) * 64 + q * 8;
      bf16x8 kf0 = *(const bf16x8*)kr;
      bf16x8 kf1 = *(const bf16x8*)(kr + 32);
      f32x4 a = {};
      a = mfma16(qa0, kf0, a);
      a = mfma16(qa1, kf1, a);
      sc[kt] = a * 0.125f;
    }

    float mx[4];
    #pragma unroll
    for (int i = 0; i < 4; ++i) {
      float m = sc[0][i];
      #pragma unroll
      for (int kt = 1; kt < 16; ++kt) m = fmaxf(m, sc[kt][i]);
      #pragma unroll
      for (int msk = 1; msk < 16; msk <<= 1) m = fmaxf(m, __shfl_xor(m, msk));
      mx[i] = m;
    }
    if (r == 0) {
      #pragma unroll
      for (int i = 0; i < 4; ++i) redm[w][q * 4 + i] = mx[i];
    }
    __syncthreads();
    #pragma unroll
    for (int i = 0; i < 4; ++i)
      mx[i] = fmaxf(fmaxf(redm[0][q * 4 + i], redm[1][q * 4 + i]),
                    fmaxf(redm[2][q * 4 + i], redm[3][q * 4 + i]));

    float sm[4] = {0.f, 0.f, 0.f, 0.f};
    #pragma unroll
    for (int kt = 0; kt < 16; ++kt)
      #pragma unroll
      for (int i = 0; i < 4; ++i) {
        float e = __expf(sc[kt][i] - mx[i]);
        sc[kt][i] = e;
        sm[i] += e;
      }
    #pragma unroll
    for (int i = 0; i < 4; ++i) {
      float s = sm[i];
      #pragma unroll
      for (int msk = 1; msk < 16; msk <<= 1) s += __shfl_xor(s, msk);
      sm[i] = s;
    }
    if (r == 0) {
      #pragma unroll
      for (int i = 0; i < 4; ++i) redsum[w][q * 4 + i] = sm[i];
    }
    __syncthreads();
    float rinv[4];
    #pragma unroll
    for (int i = 0; i < 4; ++i)
      rinv[i] = 1.0f / (redsum[0][q * 4 + i] + redsum[1][q * 4 + i] +
                        redsum[2][q * 4 + i] + redsum[3][q * 4 + i]);
    if (w == 0 && r == 0) {
      #pragma unroll
      for (int i = 0; i < 4; ++i) rinvL[q * 4 + i] = rinv[i];
    }

    #pragma unroll
    for (int kt = 0; kt < 16; ++kt) {
      int col = w * 256 + kt * 16 + r;
      #pragma unroll
      for (int i = 0; i < 4; ++i) {
        int row = q * 4 + i;
        Pl[row * 1024 + (col ^ ((row & 7) << 3))] = f2bf(sc[kt][i]);
      }
    }
    __syncthreads();

    // PV
    {
      const int d0 = w * 16;
      const ushort* vp = vt + ((size_t)bh * D + d0 + r) * S + zoff;
      f32x4 acc[4] = {};
      #pragma unroll
      for (int stp = 0; stp < 32; ++stp) {
        int t0 = stp * 32 + q * 8;
        bf16x8 pa = *(const bf16x8*)&Pl[r * 1024 + (t0 ^ ((r & 7) << 3))];
        bf16x8 vb = *(const bf16x8*)(vp + t0);
        acc[stp & 3] = mfma16(pa, vb, acc[stp & 3]);
      }
      f32x4 tot = acc[0] + acc[1] + acc[2] + acc[3];
      const int b = bh >> 3, h = bh & 7;
      #pragma unroll
      for (int i = 0; i < 4; ++i)
        concat[((size_t)b * S + s0 + q * 4 + i) * DM + h * D + d0 + r] =
            f2bf(tot[i] * rinv[i]);
    }

    // attn f32 store, full-line coalesced + non-temporal
    if (DO_STORE) {
      float* ap = attn + ((size_t)bh * S + s0) * S;
      #pragma unroll
      for (int uu = 0; uu < 16; ++uu) {
        const int row = w * 4 + (uu >> 2);
        const int chunk = uu & 3;
        const int c = chunk * 256 + l * 4;
        const int swz = (row & 7) << 3;
        ushort4 p4 = *(const ushort4*)&Pl[row * 1024 + (c ^ swz)];
        const float rv = rinvL[row];
        f32x4 o;
        o.x = bf2f(p4.x) * rv;
        o.y = bf2f(p4.y) * rv;
        o.z = bf2f(p4.z) * rv;
        o.w = bf2f(p4.w) * rv;
        __builtin_nontemporal_store(o, (f32x4*)(ap + (size_t)row * S + c));
      }
    }
    __syncthreads();                                // isolate reps (Pl reuse)
  }
}

// A: current config (ablation baseline + authoritative mainline, runs last)
__global__ __launch_bounds__(256, 4) void attn_a(
    const ushort* __restrict__ qb, const ushort* __restrict__ kb,
    const ushort* __restrict__ vt, float* __restrict__ attn,
    ushort* __restrict__ concat) {
  attn_body<2, true>(qb, kb, vt, attn, concat);
}

// B: doubled register budget (2 blocks/CU) -- reg-starvation/ILP probe
__global__ __launch_bounds__(256, 2) void attn_b(
    const ushort* __restrict__ qb, const ushort* __restrict__ kb,
    const ushort* __restrict__ vt, float* __restrict__ attn,
    ushort* __restrict__ concat) {
  attn_body<2, true>(qb, kb, vt, attn, concat);
}

// C: no attn global store -- store-cost probe
__global__ __launch_bounds__(256, 4) void attn_c(
    const ushort* __restrict__ qb, const ushort* __restrict__ kb,
    const ushort* __restrict__ vt, float* __restrict__ attn,
    ushort* __restrict__ concat) {
  attn_body<3, false>(qb, kb, vt, attn, concat);
}

// ---------------------------------------------------------------------------
// Out-proj GEMM: z[s][m] = sum_f concat[s][f] * WoT[m][f]  (M=8192,N=512,K=512)
// ---------------------------------------------------------------------------
__global__ __launch_bounds__(256) void outproj_gemm_kernel(
    const ushort* __restrict__ A, const ushort* __restrict__ Bm,
    float* __restrict__ z) {
  __shared__ ushort As[64][72], Bs[64][72];
  const int tid = threadIdx.x;
  const int m0 = blockIdx.x * 64, n0 = blockIdx.y * 64;
  const int w = tid >> 6, l = tid & 63;
  const int r = l & 15, q = l >> 4;
  const int mh = (w >> 1) * 32, nh = (w & 1) * 32;

  f32x4 acc[2][2] = {};
  const int srow = tid >> 2, sco = (tid & 3) * 16;

  for (int k0 = 0; k0 < 512; k0 += 64) {
    const ushort* ap = A + (size_t)(m0 + srow) * 512 + k0 + sco;
    const ushort* bp = Bm + (size_t)(n0 + srow) * 512 + k0 + sco;
    uint4 a0 = *(const uint4*)ap;
    uint4 a1 = *(const uint4*)(ap + 8);
    uint4 b0 = *(const uint4*)bp;
    uint4 b1 = *(const uint4*)(bp + 8);
    __syncthreads();
    *(uint4*)&As[srow][sco] = a0;
    *(uint4*)&As[srow][sco + 8] = a1;
    *(uint4*)&Bs[srow][sco] = b0;
    *(uint4*)&Bs[srow][sco + 8] = b1;
    __syncthreads();
    #pragma unroll
    for (int kk = 0; kk < 64; kk += 32) {
      bf16x8 fa0 = *(const bf16x8*)&As[mh + r][kk + q * 8];
      bf16x8 fa1 = *(const bf16x8*)&As[mh + 16 + r][kk + q * 8];
      bf16x8 fb0 = *(const bf16x8*)&Bs[nh + r][kk + q * 8];
      bf16x8 fb1 = *(const bf16x8*)&Bs[nh + 16 + r][kk + q * 8];
      acc[0][0] = mfma16(fa0, fb0, acc[0][0]);
      acc[0][1] = mfma16(fa0, fb1, acc[0][1]);
      acc[1][0] = mfma16(fa1, fb0, acc[1][0]);
      acc[1][1] = mfma16(fa1, fb1, acc[1][1]);
    }
  }

  #pragma unroll
  for (int mi = 0; mi < 2; ++mi)
    #pragma unroll
    for (int nj = 0; nj < 2; ++nj)
      #pragma unroll
      for (int i = 0; i < 4; ++i) {
        int row = m0 + mh + mi * 16 + q * 4 + i;
        int col = n0 + nh + nj * 16 + r;
        z[(size_t)row * DM + col] = acc[mi][nj][i];
      }
}

// ---------------------------------------------------------------------------
extern "C" void kernel_launch(void* const* d_in, const int* in_sizes, int n_in,
                              void* d_out, int out_size, void* d_ws, size_t ws_size,
                              hipStream_t stream) {
  const float* x  = (const float*)d_in[0];
  const float* Wq = (const float*)d_in[1];
  const float* Wk = (const float*)d_in[2];
  const float* Wv = (const float*)d_in[3];
  const float* Wo = (const float*)d_in[4];

  float* z    = (float*)d_out;                      // [B,S,DM]
  float* attn = z + (size_t)B * S * DM;             // [B,H,S,S]

  ushort* xbf    = (ushort*)d_ws;                   // [8192][512]
  ushort* WT     = xbf + (size_t)8192 * 512;        // [1536][512]
  ushort* WoT    = WT + (size_t)1536 * 512;         // [512][512]
  ushort* qb     = WoT + (size_t)512 * 512;         // [B,H,S,D]
  ushort* kb     = qb + (size_t)B * H * S * D;      // [B,H,S,D]
  ushort* vt     = kb + (size_t)B * H * S * D;      // [B,H,D,S]
  ushort* concat = vt + (size_t)B * H * S * D;      // [8192][512]

  cast_x_kernel<<<(B * S * DM / 4 + 255) / 256, 256, 0, stream>>>(x, xbf);
  prep_w_kernel<<<(1536 * 512 + 512 * 512) / 256, 256, 0, stream>>>(
      Wq, Wk, Wv, Wo, WT, WoT);
  qkv_gemm_kernel<<<dim3(8192 / 64, 1536 / 64), 256, 0, stream>>>(
      xbf, WT, qb, kb, vt);
  // --- ablation: B (reg budget), C (no attn store), A (baseline, LAST =
  // authoritative writes). All idempotent; mainline output = A's. ---
  attn_b<<<4096, 256, 0, stream>>>(qb, kb, vt, attn, concat);
  attn_c<<<4096, 256, 0, stream>>>(qb, kb, vt, attn, concat);
  attn_a<<<4096, 256, 0, stream>>>(qb, kb, vt, attn, concat);
  outproj_gemm_kernel<<<dim3(8192 / 64, 512 / 64), 256, 0, stream>>>(
      concat, WoT, z);
}

// Round 10
// 445.835 us; speedup vs baseline: 2.8204x; 2.8204x over previous
//
#include <hip/hip_runtime.h>

#define B 8
#define S 1024
#define DM 512
#define H 8
#define D 64

typedef __attribute__((ext_vector_type(8))) short bf16x8;
typedef __attribute__((ext_vector_type(4))) float f32x4;

__device__ inline f32x4 mfma16(bf16x8 a, bf16x8 b, f32x4 c) {
  return __builtin_amdgcn_mfma_f32_16x16x32_bf16(a, b, c, 0, 0, 0);
}

__device__ inline ushort f2bf(float f) {
  uint u = __float_as_uint(f);
  u += 0x7fff + ((u >> 16) & 1);   // round-to-nearest-even
  return (ushort)(u >> 16);
}

__device__ inline float bf2f(ushort u) {
  return __uint_as_float(((uint)u) << 16);
}

// ---------------------------------------------------------------------------
// Cast x [B,S,DM] f32 -> bf16, vectorized.
// ---------------------------------------------------------------------------
__global__ __launch_bounds__(256) void cast_x_kernel(const float* __restrict__ x,
                                                     ushort* __restrict__ xbf) {
  int idx = blockIdx.x * 256 + threadIdx.x;         // one float4 per thread
  float4 v = *(const float4*)(x + (size_t)idx * 4);
  ushort4 o;
  o.x = f2bf(v.x); o.y = f2bf(v.y); o.z = f2bf(v.z); o.w = f2bf(v.w);
  *(ushort4*)(xbf + (size_t)idx * 4) = o;
}

// ---------------------------------------------------------------------------
// Weight prep: WT[f][m] = W{q,k,v}[h][m][d] (f = g*512 + h*64 + d), bf16.
//              WoT[m][f] = Wo[f][m], bf16.
// ---------------------------------------------------------------------------
__global__ __launch_bounds__(256) void prep_w_kernel(
    const float* __restrict__ Wq, const float* __restrict__ Wk,
    const float* __restrict__ Wv, const float* __restrict__ Wo,
    ushort* __restrict__ WT, ushort* __restrict__ WoT) {
  int idx = blockIdx.x * 256 + threadIdx.x;
  if (idx < 1536 * 512) {
    int f = idx >> 9, m = idx & 511;
    int g = f >> 9, fl = f & 511, h = fl >> 6, d = fl & 63;
    const float* W = (g == 0) ? Wq : (g == 1) ? Wk : Wv;
    WT[idx] = f2bf(W[((size_t)h * DM + m) * D + d]);
  } else {
    int i2 = idx - 1536 * 512;                      // [0, 512*512)
    int m = i2 >> 9, f = i2 & 511;
    WoT[(size_t)m * 512 + f] = f2bf(Wo[(size_t)f * DM + m]);
  }
}

// ---------------------------------------------------------------------------
// QKV GEMM: C[s][f] = sum_m xbf[s][m] * WT[f][m]   (M=8192, N=1536, K=512)
// ---------------------------------------------------------------------------
__global__ __launch_bounds__(256) void qkv_gemm_kernel(
    const ushort* __restrict__ A, const ushort* __restrict__ Bm,
    ushort* __restrict__ qb, ushort* __restrict__ kb, ushort* __restrict__ vt) {
  __shared__ ushort As[64][72], Bs[64][72];         // +16B pad per row
  const int tid = threadIdx.x;
  const int m0 = blockIdx.x * 64, n0 = blockIdx.y * 64;
  const int w = tid >> 6, l = tid & 63;
  const int r = l & 15, q = l >> 4;
  const int mh = (w >> 1) * 32, nh = (w & 1) * 32;

  f32x4 acc[2][2] = {};
  const int srow = tid >> 2, sco = (tid & 3) * 16;  // staging: 32B per thread

  for (int k0 = 0; k0 < 512; k0 += 64) {
    const ushort* ap = A + (size_t)(m0 + srow) * 512 + k0 + sco;
    const ushort* bp = Bm + (size_t)(n0 + srow) * 512 + k0 + sco;
    uint4 a0 = *(const uint4*)ap;
    uint4 a1 = *(const uint4*)(ap + 8);
    uint4 b0 = *(const uint4*)bp;
    uint4 b1 = *(const uint4*)(bp + 8);
    __syncthreads();
    *(uint4*)&As[srow][sco] = a0;
    *(uint4*)&As[srow][sco + 8] = a1;
    *(uint4*)&Bs[srow][sco] = b0;
    *(uint4*)&Bs[srow][sco + 8] = b1;
    __syncthreads();
    #pragma unroll
    for (int kk = 0; kk < 64; kk += 32) {
      bf16x8 fa0 = *(const bf16x8*)&As[mh + r][kk + q * 8];
      bf16x8 fa1 = *(const bf16x8*)&As[mh + 16 + r][kk + q * 8];
      bf16x8 fb0 = *(const bf16x8*)&Bs[nh + r][kk + q * 8];
      bf16x8 fb1 = *(const bf16x8*)&Bs[nh + 16 + r][kk + q * 8];
      acc[0][0] = mfma16(fa0, fb0, acc[0][0]);
      acc[0][1] = mfma16(fa0, fb1, acc[0][1]);
      acc[1][0] = mfma16(fa1, fb0, acc[1][0]);
      acc[1][1] = mfma16(fa1, fb1, acc[1][1]);
    }
  }

  const int g = n0 >> 9;                            // 0=q 1=k 2=v, block-uniform
  #pragma unroll
  for (int mi = 0; mi < 2; ++mi)
    #pragma unroll
    for (int nj = 0; nj < 2; ++nj)
      #pragma unroll
      for (int i = 0; i < 4; ++i) {
        int row = m0 + mh + mi * 16 + q * 4 + i;    // global s-row
        int col = n0 + nh + nj * 16 + r;            // global f
        int bb = row >> 10, s = row & 1023;
        int fl = col & 511, h = fl >> 6, d = fl & 63;
        ushort val = f2bf(acc[mi][nj][i]);
        if (g == 0)
          qb[(((size_t)bb * H + h) * S + s) * D + d] = val;
        else if (g == 1)
          kb[(((size_t)bb * H + h) * S + s) * D + d] = val;
        else
          vt[(((size_t)bb * H + h) * D + d) * S + s] = val;
      }
}

// ---------------------------------------------------------------------------
// DIAGNOSTIC: byte-identical production attn (R8 version), grid-doubled so
// each tile is computed by 2 blocks (identical values -> benign duplicate
// writes). ~268us dispatch => cracks rocprof top-5 with the TRUE production
// VGPR count / FETCH / WRITE (spill shows as WRITE >> 530 MB legit).
// ---------------------------------------------------------------------------
__global__ __launch_bounds__(256, 4) void attn_plain2x(
    const ushort* __restrict__ qb, const ushort* __restrict__ kb,
    const ushort* __restrict__ vt, float* __restrict__ attn,
    ushort* __restrict__ concat) {
  __shared__ ushort Pl[16 * 1024];
  __shared__ float redm[4][16], redsum[4][16];
  __shared__ float rinvL[16];
  const int tid = threadIdx.x;
  const int w = tid >> 6, l = tid & 63;
  const int r = l & 15, q = l >> 4;

  const int n = blockIdx.x >> 1;                    // 2 blocks per tile
  const int rank = n >> 3;
  const int bh = (n & 7) * 8 + (rank >> 6);
  const int s0 = (rank & 63) * 16;

  const ushort* qp = qb + ((size_t)bh * S + s0) * D;
  bf16x8 qa0 = *(const bf16x8*)(qp + r * 64 + q * 8);
  bf16x8 qa1 = *(const bf16x8*)(qp + r * 64 + 32 + q * 8);

  const ushort* kp = kb + (size_t)bh * S * D;
  f32x4 sc[16];
  #pragma unroll
  for (int kt = 0; kt < 16; ++kt) {
    const ushort* kr = kp + (size_t)(w * 256 + kt * 16 + r) * 64 + q * 8;
    bf16x8 kf0 = *(const bf16x8*)kr;
    bf16x8 kf1 = *(const bf16x8*)(kr + 32);
    f32x4 a = {};
    a = mfma16(qa0, kf0, a);
    a = mfma16(qa1, kf1, a);
    sc[kt] = a * 0.125f;
  }

  float mx[4];
  #pragma unroll
  for (int i = 0; i < 4; ++i) {
    float m = sc[0][i];
    #pragma unroll
    for (int kt = 1; kt < 16; ++kt) m = fmaxf(m, sc[kt][i]);
    #pragma unroll
    for (int msk = 1; msk < 16; msk <<= 1) m = fmaxf(m, __shfl_xor(m, msk));
    mx[i] = m;
  }
  if (r == 0) {
    #pragma unroll
    for (int i = 0; i < 4; ++i) redm[w][q * 4 + i] = mx[i];
  }
  __syncthreads();
  #pragma unroll
  for (int i = 0; i < 4; ++i)
    mx[i] = fmaxf(fmaxf(redm[0][q * 4 + i], redm[1][q * 4 + i]),
                  fmaxf(redm[2][q * 4 + i], redm[3][q * 4 + i]));

  float sm[4] = {0.f, 0.f, 0.f, 0.f};
  #pragma unroll
  for (int kt = 0; kt < 16; ++kt)
    #pragma unroll
    for (int i = 0; i < 4; ++i) {
      float e = __expf(sc[kt][i] - mx[i]);
      sc[kt][i] = e;
      sm[i] += e;
    }
  #pragma unroll
  for (int i = 0; i < 4; ++i) {
    float s = sm[i];
    #pragma unroll
    for (int msk = 1; msk < 16; msk <<= 1) s += __shfl_xor(s, msk);
    sm[i] = s;
  }
  if (r == 0) {
    #pragma unroll
    for (int i = 0; i < 4; ++i) redsum[w][q * 4 + i] = sm[i];
  }
  __syncthreads();
  float rinv[4];
  #pragma unroll
  for (int i = 0; i < 4; ++i)
    rinv[i] = 1.0f / (redsum[0][q * 4 + i] + redsum[1][q * 4 + i] +
                      redsum[2][q * 4 + i] + redsum[3][q * 4 + i]);
  if (w == 0 && r == 0) {
    #pragma unroll
    for (int i = 0; i < 4; ++i) rinvL[q * 4 + i] = rinv[i];
  }

  #pragma unroll
  for (int kt = 0; kt < 16; ++kt) {
    int col = w * 256 + kt * 16 + r;
    #pragma unroll
    for (int i = 0; i < 4; ++i) {
      int row = q * 4 + i;
      Pl[row * 1024 + (col ^ ((row & 7) << 3))] = f2bf(sc[kt][i]);
    }
  }
  __syncthreads();

  {
    const int d0 = w * 16;
    const ushort* vp = vt + ((size_t)bh * D + d0 + r) * S;
    f32x4 acc[4] = {};
    #pragma unroll
    for (int stp = 0; stp < 32; ++stp) {
      int t0 = stp * 32 + q * 8;
      bf16x8 pa = *(const bf16x8*)&Pl[r * 1024 + (t0 ^ ((r & 7) << 3))];
      bf16x8 vb = *(const bf16x8*)(vp + t0);
      acc[stp & 3] = mfma16(pa, vb, acc[stp & 3]);
    }
    f32x4 tot = acc[0] + acc[1] + acc[2] + acc[3];
    const int b = bh >> 3, h = bh & 7;
    #pragma unroll
    for (int i = 0; i < 4; ++i)
      concat[((size_t)b * S + s0 + q * 4 + i) * DM + h * D + d0 + r] =
          f2bf(tot[i] * rinv[i]);
  }

  {
    float* ap = attn + ((size_t)bh * S + s0) * S;
    #pragma unroll
    for (int uu = 0; uu < 16; ++uu) {
      const int row = w * 4 + (uu >> 2);
      const int chunk = uu & 3;
      const int c = chunk * 256 + l * 4;
      const int swz = (row & 7) << 3;
      ushort4 p4 = *(const ushort4*)&Pl[row * 1024 + (c ^ swz)];
      const float rv = rinvL[row];
      f32x4 o;
      o.x = bf2f(p4.x) * rv;
      o.y = bf2f(p4.y) * rv;
      o.z = bf2f(p4.z) * rv;
      o.w = bf2f(p4.w) * rv;
      __builtin_nontemporal_store(o, (f32x4*)(ap + (size_t)row * S + c));
    }
  }
}

// ---------------------------------------------------------------------------
// CANDIDATE attn_v2: 8 waves x 512 threads per 16-row tile.
//  - wave w owns k-cols [w*128, w*128+128): sc[8] (32 VGPR, was 64)
//  - 24 waves/CU via __launch_bounds__(512,6) (was 16) -> +50% TLP
//  - tail role-split: waves 0-3 PV, waves 4-7 stream attn stores (overlap)
// Work conserved: same mfma/exp totals, same Pl layout/swizzle.
// ---------------------------------------------------------------------------
__global__ __launch_bounds__(512, 6) void attn_v2(
    const ushort* __restrict__ qb, const ushort* __restrict__ kb,
    const ushort* __restrict__ vt, float* __restrict__ attn,
    ushort* __restrict__ concat) {
  __shared__ ushort Pl[16 * 1024];                  // 32 KB swizzled bf16 P
  __shared__ float redm[8][16], redsum[8][16];      // 1 KB
  __shared__ float rinvL[16];
  const int tid = threadIdx.x;
  const int w = tid >> 6, l = tid & 63;
  const int r = l & 15, q = l >> 4;

  const int n = blockIdx.x;
  const int rank = n >> 3;
  const int bh = (n & 7) * 8 + (rank >> 6);
  const int s0 = (rank & 63) * 16;

  const ushort* qp = qb + ((size_t)bh * S + s0) * D;
  bf16x8 qa0 = *(const bf16x8*)(qp + r * 64 + q * 8);
  bf16x8 qa1 = *(const bf16x8*)(qp + r * 64 + 32 + q * 8);

  // scores: sc[kt][i] = S[q*4+i][w*128 + kt*16 + r] * 1/8   (kt < 8)
  const ushort* kp = kb + (size_t)bh * S * D;
  f32x4 sc[8];
  #pragma unroll
  for (int kt = 0; kt < 8; ++kt) {
    const ushort* kr = kp + (size_t)(w * 128 + kt * 16 + r) * 64 + q * 8;
    bf16x8 kf0 = *(const bf16x8*)kr;
    bf16x8 kf1 = *(const bf16x8*)(kr + 32);
    f32x4 a = {};
    a = mfma16(qa0, kf0, a);
    a = mfma16(qa1, kf1, a);
    sc[kt] = a * 0.125f;
  }

  // row max: lane-local (8), cross-r shuffle, cross-wave (8) via LDS
  float mx[4];
  #pragma unroll
  for (int i = 0; i < 4; ++i) {
    float m = sc[0][i];
    #pragma unroll
    for (int kt = 1; kt < 8; ++kt) m = fmaxf(m, sc[kt][i]);
    #pragma unroll
    for (int msk = 1; msk < 16; msk <<= 1) m = fmaxf(m, __shfl_xor(m, msk));
    mx[i] = m;
  }
  if (r == 0) {
    #pragma unroll
    for (int i = 0; i < 4; ++i) redm[w][q * 4 + i] = mx[i];
  }
  __syncthreads();
  #pragma unroll
  for (int i = 0; i < 4; ++i) {
    int rr = q * 4 + i;
    float m = fmaxf(fmaxf(redm[0][rr], redm[1][rr]),
                    fmaxf(redm[2][rr], redm[3][rr]));
    m = fmaxf(m, fmaxf(fmaxf(redm[4][rr], redm[5][rr]),
                       fmaxf(redm[6][rr], redm[7][rr])));
    mx[i] = m;
  }

  // exp + row sums
  float sm[4] = {0.f, 0.f, 0.f, 0.f};
  #pragma unroll
  for (int kt = 0; kt < 8; ++kt)
    #pragma unroll
    for (int i = 0; i < 4; ++i) {
      float e = __expf(sc[kt][i] - mx[i]);
      sc[kt][i] = e;
      sm[i] += e;
    }
  #pragma unroll
  for (int i = 0; i < 4; ++i) {
    float s = sm[i];
    #pragma unroll
    for (int msk = 1; msk < 16; msk <<= 1) s += __shfl_xor(s, msk);
    sm[i] = s;
  }
  if (r == 0) {
    #pragma unroll
    for (int i = 0; i < 4; ++i) redsum[w][q * 4 + i] = sm[i];
  }
  __syncthreads();
  float rinv[4];
  #pragma unroll
  for (int i = 0; i < 4; ++i) {
    int rr = q * 4 + i;
    float s = (redsum[0][rr] + redsum[1][rr]) + (redsum[2][rr] + redsum[3][rr]) +
              (redsum[4][rr] + redsum[5][rr]) + (redsum[6][rr] + redsum[7][rr]);
    rinv[i] = 1.0f / s;
  }
  if (w == 0 && r == 0) {
    #pragma unroll
    for (int i = 0; i < 4; ++i) rinvL[q * 4 + i] = rinv[i];
  }

  // P -> swizzled LDS (wave w covers cols [w*128, w*128+128))
  #pragma unroll
  for (int kt = 0; kt < 8; ++kt) {
    int col = w * 128 + kt * 16 + r;
    #pragma unroll
    for (int i = 0; i < 4; ++i) {
      int row = q * 4 + i;
      Pl[row * 1024 + (col ^ ((row & 7) << 3))] = f2bf(sc[kt][i]);
    }
  }
  __syncthreads();

  if (w < 4) {
    // PV: wave w owns d-tile [w*16, w*16+16)
    const int d0 = w * 16;
    const ushort* vp = vt + ((size_t)bh * D + d0 + r) * S;
    f32x4 acc[4] = {};
    #pragma unroll
    for (int stp = 0; stp < 32; ++stp) {
      int t0 = stp * 32 + q * 8;
      bf16x8 pa = *(const bf16x8*)&Pl[r * 1024 + (t0 ^ ((r & 7) << 3))];
      bf16x8 vb = *(const bf16x8*)(vp + t0);
      acc[stp & 3] = mfma16(pa, vb, acc[stp & 3]);
    }
    f32x4 tot = acc[0] + acc[1] + acc[2] + acc[3];
    const int b = bh >> 3, h = bh & 7;
    #pragma unroll
    for (int i = 0; i < 4; ++i)
      concat[((size_t)b * S + s0 + q * 4 + i) * DM + h * D + d0 + r] =
          f2bf(tot[i] * rinv[i]);
  } else {
    // attn f32 stores, full-line nt: wave (w-4) streams rows [(w-4)*4, +4)
    const int ws = w - 4;
    float* ap = attn + ((size_t)bh * S + s0) * S;
    #pragma unroll
    for (int uu = 0; uu < 16; ++uu) {
      const int row = ws * 4 + (uu >> 2);
      const int chunk = uu & 3;
      const int c = chunk * 256 + l * 4;
      const int swz = (row & 7) << 3;
      ushort4 p4 = *(const ushort4*)&Pl[row * 1024 + (c ^ swz)];
      const float rv = rinvL[row];
      f32x4 o;
      o.x = bf2f(p4.x) * rv;
      o.y = bf2f(p4.y) * rv;
      o.z = bf2f(p4.z) * rv;
      o.w = bf2f(p4.w) * rv;
      __builtin_nontemporal_store(o, (f32x4*)(ap + (size_t)row * S + c));
    }
  }
}

// ---------------------------------------------------------------------------
// Out-proj GEMM: z[s][m] = sum_f concat[s][f] * WoT[m][f]  (M=8192,N=512,K=512)
// ---------------------------------------------------------------------------
__global__ __launch_bounds__(256) void outproj_gemm_kernel(
    const ushort* __restrict__ A, const ushort* __restrict__ Bm,
    float* __restrict__ z) {
  __shared__ ushort As[64][72], Bs[64][72];
  const int tid = threadIdx.x;
  const int m0 = blockIdx.x * 64, n0 = blockIdx.y * 64;
  const int w = tid >> 6, l = tid & 63;
  const int r = l & 15, q = l >> 4;
  const int mh = (w >> 1) * 32, nh = (w & 1) * 32;

  f32x4 acc[2][2] = {};
  const int srow = tid >> 2, sco = (tid & 3) * 16;

  for (int k0 = 0; k0 < 512; k0 += 64) {
    const ushort* ap = A + (size_t)(m0 + srow) * 512 + k0 + sco;
    const ushort* bp = Bm + (size_t)(n0 + srow) * 512 + k0 + sco;
    uint4 a0 = *(const uint4*)ap;
    uint4 a1 = *(const uint4*)(ap + 8);
    uint4 b0 = *(const uint4*)bp;
    uint4 b1 = *(const uint4*)(bp + 8);
    __syncthreads();
    *(uint4*)&As[srow][sco] = a0;
    *(uint4*)&As[srow][sco + 8] = a1;
    *(uint4*)&Bs[srow][sco] = b0;
    *(uint4*)&Bs[srow][sco + 8] = b1;
    __syncthreads();
    #pragma unroll
    for (int kk = 0; kk < 64; kk += 32) {
      bf16x8 fa0 = *(const bf16x8*)&As[mh + r][kk + q * 8];
      bf16x8 fa1 = *(const bf16x8*)&As[mh + 16 + r][kk + q * 8];
      bf16x8 fb0 = *(const bf16x8*)&Bs[nh + r][kk + q * 8];
      bf16x8 fb1 = *(const bf16x8*)&Bs[nh + 16 + r][kk + q * 8];
      acc[0][0] = mfma16(fa0, fb0, acc[0][0]);
      acc[0][1] = mfma16(fa0, fb1, acc[0][1]);
      acc[1][0] = mfma16(fa1, fb0, acc[1][0]);
      acc[1][1] = mfma16(fa1, fb1, acc[1][1]);
    }
  }

  #pragma unroll
  for (int mi = 0; mi < 2; ++mi)
    #pragma unroll
    for (int nj = 0; nj < 2; ++nj)
      #pragma unroll
      for (int i = 0; i < 4; ++i) {
        int row = m0 + mh + mi * 16 + q * 4 + i;
        int col = n0 + nh + nj * 16 + r;
        z[(size_t)row * DM + col] = acc[mi][nj][i];
      }
}

// ---------------------------------------------------------------------------
extern "C" void kernel_launch(void* const* d_in, const int* in_sizes, int n_in,
                              void* d_out, int out_size, void* d_ws, size_t ws_size,
                              hipStream_t stream) {
  const float* x  = (const float*)d_in[0];
  const float* Wq = (const float*)d_in[1];
  const float* Wk = (const float*)d_in[2];
  const float* Wv = (const float*)d_in[3];
  const float* Wo = (const float*)d_in[4];

  float* z    = (float*)d_out;                      // [B,S,DM]
  float* attn = z + (size_t)B * S * DM;             // [B,H,S,S]

  ushort* xbf    = (ushort*)d_ws;                   // [8192][512]
  ushort* WT     = xbf + (size_t)8192 * 512;        // [1536][512]
  ushort* WoT    = WT + (size_t)1536 * 512;         // [512][512]
  ushort* qb     = WoT + (size_t)512 * 512;         // [B,H,S,D]
  ushort* kb     = qb + (size_t)B * H * S * D;      // [B,H,S,D]
  ushort* vt     = kb + (size_t)B * H * S * D;      // [B,H,D,S]
  ushort* concat = vt + (size_t)B * H * S * D;      // [8192][512]

  cast_x_kernel<<<(B * S * DM / 4 + 255) / 256, 256, 0, stream>>>(x, xbf);
  prep_w_kernel<<<(1536 * 512 + 512 * 512) / 256, 256, 0, stream>>>(
      Wq, Wk, Wv, Wo, WT, WoT);
  qkv_gemm_kernel<<<dim3(8192 / 64, 1536 / 64), 256, 0, stream>>>(
      xbf, WT, qb, kb, vt);
  // diagnostic first (duplicate identical writes), authoritative v2 last
  attn_plain2x<<<8192, 256, 0, stream>>>(qb, kb, vt, attn, concat);
  attn_v2<<<4096, 512, 0, stream>>>(qb, kb, vt, attn, concat);
  outproj_gemm_kernel<<<dim3(8192 / 64, 512 / 64), 256, 0, stream>>>(
      concat, WoT, z);
}

// Round 11
// 195.035 us; speedup vs baseline: 6.4472x; 2.2859x over previous
//
#include <hip/hip_runtime.h>

#define B 8
#define S 1024
#define DM 512
#define H 8
#define D 64

typedef __attribute__((ext_vector_type(8))) short bf16x8;
typedef __attribute__((ext_vector_type(4))) float f32x4;

__device__ inline f32x4 mfma16(bf16x8 a, bf16x8 b, f32x4 c) {
  return __builtin_amdgcn_mfma_f32_16x16x32_bf16(a, b, c, 0, 0, 0);
}

__device__ inline ushort f2bf(float f) {
  uint u = __float_as_uint(f);
  u += 0x7fff + ((u >> 16) & 1);   // round-to-nearest-even
  return (ushort)(u >> 16);
}

__device__ inline float bf2f(ushort u) {
  return __uint_as_float(((uint)u) << 16);
}

// ---------------------------------------------------------------------------
// Cast x [B,S,DM] f32 -> bf16, vectorized.
// ---------------------------------------------------------------------------
__global__ __launch_bounds__(256) void cast_x_kernel(const float* __restrict__ x,
                                                     ushort* __restrict__ xbf) {
  int idx = blockIdx.x * 256 + threadIdx.x;         // one float4 per thread
  float4 v = *(const float4*)(x + (size_t)idx * 4);
  ushort4 o;
  o.x = f2bf(v.x); o.y = f2bf(v.y); o.z = f2bf(v.z); o.w = f2bf(v.w);
  *(ushort4*)(xbf + (size_t)idx * 4) = o;
}

// ---------------------------------------------------------------------------
// Weight prep: WT[f][m] = W{q,k,v}[h][m][d] (f = g*512 + h*64 + d), bf16.
//              WoT[m][f] = Wo[f][m], bf16.
// ---------------------------------------------------------------------------
__global__ __launch_bounds__(256) void prep_w_kernel(
    const float* __restrict__ Wq, const float* __restrict__ Wk,
    const float* __restrict__ Wv, const float* __restrict__ Wo,
    ushort* __restrict__ WT, ushort* __restrict__ WoT) {
  int idx = blockIdx.x * 256 + threadIdx.x;
  if (idx < 1536 * 512) {
    int f = idx >> 9, m = idx & 511;
    int g = f >> 9, fl = f & 511, h = fl >> 6, d = fl & 63;
    const float* W = (g == 0) ? Wq : (g == 1) ? Wk : Wv;
    WT[idx] = f2bf(W[((size_t)h * DM + m) * D + d]);
  } else {
    int i2 = idx - 1536 * 512;                      // [0, 512*512)
    int m = i2 >> 9, f = i2 & 511;
    WoT[(size_t)m * 512 + f] = f2bf(Wo[(size_t)f * DM + m]);
  }
}

// ---------------------------------------------------------------------------
// QKV GEMM: C[s][f] = sum_m xbf[s][m] * WT[f][m]   (M=8192, N=1536, K=512)
// ---------------------------------------------------------------------------
__global__ __launch_bounds__(256) void qkv_gemm_kernel(
    const ushort* __restrict__ A, const ushort* __restrict__ Bm,
    ushort* __restrict__ qb, ushort* __restrict__ kb, ushort* __restrict__ vt) {
  __shared__ ushort As[64][72], Bs[64][72];         // +16B pad per row
  const int tid = threadIdx.x;
  const int m0 = blockIdx.x * 64, n0 = blockIdx.y * 64;
  const int w = tid >> 6, l = tid & 63;
  const int r = l & 15, q = l >> 4;
  const int mh = (w >> 1) * 32, nh = (w & 1) * 32;

  f32x4 acc[2][2] = {};
  const int srow = tid >> 2, sco = (tid & 3) * 16;  // staging: 32B per thread

  for (int k0 = 0; k0 < 512; k0 += 64) {
    const ushort* ap = A + (size_t)(m0 + srow) * 512 + k0 + sco;
    const ushort* bp = Bm + (size_t)(n0 + srow) * 512 + k0 + sco;
    uint4 a0 = *(const uint4*)ap;
    uint4 a1 = *(const uint4*)(ap + 8);
    uint4 b0 = *(const uint4*)bp;
    uint4 b1 = *(const uint4*)(bp + 8);
    __syncthreads();
    *(uint4*)&As[srow][sco] = a0;
    *(uint4*)&As[srow][sco + 8] = a1;
    *(uint4*)&Bs[srow][sco] = b0;
    *(uint4*)&Bs[srow][sco + 8] = b1;
    __syncthreads();
    #pragma unroll
    for (int kk = 0; kk < 64; kk += 32) {
      bf16x8 fa0 = *(const bf16x8*)&As[mh + r][kk + q * 8];
      bf16x8 fa1 = *(const bf16x8*)&As[mh + 16 + r][kk + q * 8];
      bf16x8 fb0 = *(const bf16x8*)&Bs[nh + r][kk + q * 8];
      bf16x8 fb1 = *(const bf16x8*)&Bs[nh + 16 + r][kk + q * 8];
      acc[0][0] = mfma16(fa0, fb0, acc[0][0]);
      acc[0][1] = mfma16(fa0, fb1, acc[0][1]);
      acc[1][0] = mfma16(fa1, fb0, acc[1][0]);
      acc[1][1] = mfma16(fa1, fb1, acc[1][1]);
    }
  }

  const int g = n0 >> 9;                            // 0=q 1=k 2=v, block-uniform
  #pragma unroll
  for (int mi = 0; mi < 2; ++mi)
    #pragma unroll
    for (int nj = 0; nj < 2; ++nj)
      #pragma unroll
      for (int i = 0; i < 4; ++i) {
        int row = m0 + mh + mi * 16 + q * 4 + i;    // global s-row
        int col = n0 + nh + nj * 16 + r;            // global f
        int bb = row >> 10, s = row & 1023;
        int fl = col & 511, h = fl >> 6, d = fl & 63;
        ushort val = f2bf(acc[mi][nj][i]);
        if (g == 0)
          qb[(((size_t)bb * H + h) * S + s) * D + d] = val;
        else if (g == 1)
          kb[(((size_t)bb * H + h) * S + s) * D + d] = val;
        else
          vt[(((size_t)bb * H + h) * D + d) * S + s] = val;
      }
}

// ---------------------------------------------------------------------------
// Attention v3: 8 waves x 512 threads per 16-row tile (R10's v2, measured
// 116us vs 134 for 4-wave) plus:
//  - SINGLE-barrier online softmax: per-wave local max + exp + local sum,
//    one barrier, cross-wave combine tot = sum_w s_w*exp(m_w-m); the
//    per-wave correction exp(m_w-m) folds into the Pl write. (3 bar -> 2)
//  - V prefetch depth 4: V loads are P-independent; issue them before the
//    Pl barrier so HBM/L2 latency hides under LDS writes + barrier.
//  - tail role-split: waves 0-3 PV, waves 4-7 stream attn full-line nt
//    stores (overlaps store burst with MFMA).
// Clean-instrument facts (R10): FETCH 24.7MB (K/V read once, no locality
// problem, no spill), latency-bound (VALU 23%, MFMA 5%, nothing saturated).
// ---------------------------------------------------------------------------
__global__ __launch_bounds__(512, 6) void attn_v3(
    const ushort* __restrict__ qb, const ushort* __restrict__ kb,
    const ushort* __restrict__ vt, float* __restrict__ attn,
    ushort* __restrict__ concat) {
  __shared__ ushort Pl[16 * 1024];                  // 32 KB swizzled bf16 P
  __shared__ float redm[8][16], redsum[8][16];      // 1 KB
  __shared__ float rinvL[16];
  const int tid = threadIdx.x;
  const int w = tid >> 6, l = tid & 63;
  const int r = l & 15, q = l >> 4;

  const int n = blockIdx.x;
  const int rank = n >> 3;
  const int bh = (n & 7) * 8 + (rank >> 6);
  const int s0 = (rank & 63) * 16;

  const ushort* qp = qb + ((size_t)bh * S + s0) * D;
  bf16x8 qa0 = *(const bf16x8*)(qp + r * 64 + q * 8);
  bf16x8 qa1 = *(const bf16x8*)(qp + r * 64 + 32 + q * 8);

  // scores: sc[kt][i] = S[q*4+i][w*128 + kt*16 + r] * 1/8   (kt < 8)
  const ushort* kp = kb + (size_t)bh * S * D;
  f32x4 sc[8];
  #pragma unroll
  for (int kt = 0; kt < 8; ++kt) {
    const ushort* kr = kp + (size_t)(w * 128 + kt * 16 + r) * 64 + q * 8;
    bf16x8 kf0 = *(const bf16x8*)kr;
    bf16x8 kf1 = *(const bf16x8*)(kr + 32);
    f32x4 a = {};
    a = mfma16(qa0, kf0, a);
    a = mfma16(qa1, kf1, a);
    sc[kt] = a * 0.125f;
  }

  // wave-local max over this wave's 128 cols (lane-local + r-shuffle)
  float mxl[4];
  #pragma unroll
  for (int i = 0; i < 4; ++i) {
    float m = sc[0][i];
    #pragma unroll
    for (int kt = 1; kt < 8; ++kt) m = fmaxf(m, sc[kt][i]);
    #pragma unroll
    for (int msk = 1; msk < 16; msk <<= 1) m = fmaxf(m, __shfl_xor(m, msk));
    mxl[i] = m;
  }

  // exp relative to LOCAL max + wave-local sums
  float sml[4] = {0.f, 0.f, 0.f, 0.f};
  #pragma unroll
  for (int kt = 0; kt < 8; ++kt)
    #pragma unroll
    for (int i = 0; i < 4; ++i) {
      float e = __expf(sc[kt][i] - mxl[i]);
      sc[kt][i] = e;
      sml[i] += e;
    }
  #pragma unroll
  for (int i = 0; i < 4; ++i) {
    float s = sml[i];
    #pragma unroll
    for (int msk = 1; msk < 16; msk <<= 1) s += __shfl_xor(s, msk);
    sml[i] = s;
  }
  if (r == 0) {
    #pragma unroll
    for (int i = 0; i < 4; ++i) {
      redm[w][q * 4 + i] = mxl[i];
      redsum[w][q * 4 + i] = sml[i];
    }
  }
  __syncthreads();                                  // barrier 1 (only reduce)

  // cross-wave combine: m = max_w m_w; tot = sum_w s_w * exp(m_w - m);
  // this wave's P correction = exp(m_local - m).
  float rinv[4], corr[4];
  #pragma unroll
  for (int i = 0; i < 4; ++i) {
    const int rr = q * 4 + i;
    float m = redm[0][rr];
    #pragma unroll
    for (int ww = 1; ww < 8; ++ww) m = fmaxf(m, redm[ww][rr]);
    float tot = 0.f;
    #pragma unroll
    for (int ww = 0; ww < 8; ++ww)
      tot += redsum[ww][rr] * __expf(redm[ww][rr] - m);
    rinv[i] = 1.0f / tot;
    corr[i] = __expf(mxl[i] - m);
  }
  if (w == 0 && r == 0) {
    #pragma unroll
    for (int i = 0; i < 4; ++i) rinvL[q * 4 + i] = rinv[i];
  }

  // V prefetch (waves 0-3): first 4 PV steps, independent of Pl
  const ushort* vp = vt + ((size_t)bh * D + (w & 3) * 16 + r) * S;
  bf16x8 vpre[4];
  if (w < 4) {
    #pragma unroll
    for (int pp = 0; pp < 4; ++pp)
      vpre[pp] = *(const bf16x8*)(vp + pp * 32 + q * 8);
  }

  // P -> swizzled LDS with per-wave correction folded in
  #pragma unroll
  for (int kt = 0; kt < 8; ++kt) {
    int col = w * 128 + kt * 16 + r;
    #pragma unroll
    for (int i = 0; i < 4; ++i) {
      int row = q * 4 + i;
      Pl[row * 1024 + (col ^ ((row & 7) << 3))] = f2bf(sc[kt][i] * corr[i]);
    }
  }
  __syncthreads();                                  // barrier 2 (Pl ready)

  if (w < 4) {
    // PV: wave w owns d-tile [w*16, w*16+16)
    f32x4 acc[4] = {};
    #pragma unroll
    for (int stp = 0; stp < 32; ++stp) {
      int t0 = stp * 32 + q * 8;
      bf16x8 pa = *(const bf16x8*)&Pl[r * 1024 + (t0 ^ ((r & 7) << 3))];
      bf16x8 vb = (stp < 4) ? vpre[stp] : *(const bf16x8*)(vp + t0);
      acc[stp & 3] = mfma16(pa, vb, acc[stp & 3]);
    }
    f32x4 tot = acc[0] + acc[1] + acc[2] + acc[3];
    const int b = bh >> 3, h = bh & 7;
    const int d0 = w * 16;
    #pragma unroll
    for (int i = 0; i < 4; ++i)
      concat[((size_t)b * S + s0 + q * 4 + i) * DM + h * D + d0 + r] =
          f2bf(tot[i] * rinv[i]);
  } else {
    // attn f32 stores, full-line nt: wave (w-4) streams rows [(w-4)*4, +4)
    const int ws = w - 4;
    float* ap = attn + ((size_t)bh * S + s0) * S;
    #pragma unroll
    for (int uu = 0; uu < 16; ++uu) {
      const int row = ws * 4 + (uu >> 2);
      const int chunk = uu & 3;
      const int c = chunk * 256 + l * 4;
      const int swz = (row & 7) << 3;
      ushort4 p4 = *(const ushort4*)&Pl[row * 1024 + (c ^ swz)];
      const float rv = rinvL[row];
      f32x4 o;
      o.x = bf2f(p4.x) * rv;
      o.y = bf2f(p4.y) * rv;
      o.z = bf2f(p4.z) * rv;
      o.w = bf2f(p4.w) * rv;
      __builtin_nontemporal_store(o, (f32x4*)(ap + (size_t)row * S + c));
    }
  }
}

// ---------------------------------------------------------------------------
// Out-proj GEMM: z[s][m] = sum_f concat[s][f] * WoT[m][f]  (M=8192,N=512,K=512)
// ---------------------------------------------------------------------------
__global__ __launch_bounds__(256) void outproj_gemm_kernel(
    const ushort* __restrict__ A, const ushort* __restrict__ Bm,
    float* __restrict__ z) {
  __shared__ ushort As[64][72], Bs[64][72];
  const int tid = threadIdx.x;
  const int m0 = blockIdx.x * 64, n0 = blockIdx.y * 64;
  const int w = tid >> 6, l = tid & 63;
  const int r = l & 15, q = l >> 4;
  const int mh = (w >> 1) * 32, nh = (w & 1) * 32;

  f32x4 acc[2][2] = {};
  const int srow = tid >> 2, sco = (tid & 3) * 16;

  for (int k0 = 0; k0 < 512; k0 += 64) {
    const ushort* ap = A + (size_t)(m0 + srow) * 512 + k0 + sco;
    const ushort* bp = Bm + (size_t)(n0 + srow) * 512 + k0 + sco;
    uint4 a0 = *(const uint4*)ap;
    uint4 a1 = *(const uint4*)(ap + 8);
    uint4 b0 = *(const uint4*)bp;
    uint4 b1 = *(const uint4*)(bp + 8);
    __syncthreads();
    *(uint4*)&As[srow][sco] = a0;
    *(uint4*)&As[srow][sco + 8] = a1;
    *(uint4*)&Bs[srow][sco] = b0;
    *(uint4*)&Bs[srow][sco + 8] = b1;
    __syncthreads();
    #pragma unroll
    for (int kk = 0; kk < 64; kk += 32) {
      bf16x8 fa0 = *(const bf16x8*)&As[mh + r][kk + q * 8];
      bf16x8 fa1 = *(const bf16x8*)&As[mh + 16 + r][kk + q * 8];
      bf16x8 fb0 = *(const bf16x8*)&Bs[nh + r][kk + q * 8];
      bf16x8 fb1 = *(const bf16x8*)&Bs[nh + 16 + r][kk + q * 8];
      acc[0][0] = mfma16(fa0, fb0, acc[0][0]);
      acc[0][1] = mfma16(fa0, fb1, acc[0][1]);
      acc[1][0] = mfma16(fa1, fb0, acc[1][0]);
      acc[1][1] = mfma16(fa1, fb1, acc[1][1]);
    }
  }

  #pragma unroll
  for (int mi = 0; mi < 2; ++mi)
    #pragma unroll
    for (int nj = 0; nj < 2; ++nj)
      #pragma unroll
      for (int i = 0; i < 4; ++i) {
        int row = m0 + mh + mi * 16 + q * 4 + i;
        int col = n0 + nh + nj * 16 + r;
        z[(size_t)row * DM + col] = acc[mi][nj][i];
      }
}

// ---------------------------------------------------------------------------
extern "C" void kernel_launch(void* const* d_in, const int* in_sizes, int n_in,
                              void* d_out, int out_size, void* d_ws, size_t ws_size,
                              hipStream_t stream) {
  const float* x  = (const float*)d_in[0];
  const float* Wq = (const float*)d_in[1];
  const float* Wk = (const float*)d_in[2];
  const float* Wv = (const float*)d_in[3];
  const float* Wo = (const float*)d_in[4];

  float* z    = (float*)d_out;                      // [B,S,DM]
  float* attn = z + (size_t)B * S * DM;             // [B,H,S,S]

  ushort* xbf    = (ushort*)d_ws;                   // [8192][512]
  ushort* WT     = xbf + (size_t)8192 * 512;        // [1536][512]
  ushort* WoT    = WT + (size_t)1536 * 512;         // [512][512]
  ushort* qb     = WoT + (size_t)512 * 512;         // [B,H,S,D]
  ushort* kb     = qb + (size_t)B * H * S * D;      // [B,H,S,D]
  ushort* vt     = kb + (size_t)B * H * S * D;      // [B,H,D,S]
  ushort* concat = vt + (size_t)B * H * S * D;      // [8192][512]

  cast_x_kernel<<<(B * S * DM / 4 + 255) / 256, 256, 0, stream>>>(x, xbf);
  prep_w_kernel<<<(1536 * 512 + 512 * 512) / 256, 256, 0, stream>>>(
      Wq, Wk, Wv, Wo, WT, WoT);
  qkv_gemm_kernel<<<dim3(8192 / 64, 1536 / 64), 256, 0, stream>>>(
      xbf, WT, qb, kb, vt);
  attn_v3<<<4096, 512, 0, stream>>>(qb, kb, vt, attn, concat);
  outproj_gemm_kernel<<<dim3(8192 / 64, 512 / 64), 256, 0, stream>>>(
      concat, WoT, z);
}

// Round 12
// 194.400 us; speedup vs baseline: 6.4683x; 1.0033x over previous
//
#include <hip/hip_runtime.h>

#define B 8
#define S 1024
#define DM 512
#define H 8
#define D 64

typedef __attribute__((ext_vector_type(8))) short bf16x8;
typedef __attribute__((ext_vector_type(4))) float f32x4;

__device__ inline f32x4 mfma16(bf16x8 a, bf16x8 b, f32x4 c) {
  return __builtin_amdgcn_mfma_f32_16x16x32_bf16(a, b, c, 0, 0, 0);
}

__device__ inline ushort f2bf(float f) {
  uint u = __float_as_uint(f);
  u += 0x7fff + ((u >> 16) & 1);   // round-to-nearest-even
  return (ushort)(u >> 16);
}

__device__ inline float bf2f(ushort u) {
  return __uint_as_float(((uint)u) << 16);
}

// ---------------------------------------------------------------------------
// Cast x [B,S,DM] f32 -> bf16, vectorized.
// ---------------------------------------------------------------------------
__global__ __launch_bounds__(256) void cast_x_kernel(const float* __restrict__ x,
                                                     ushort* __restrict__ xbf) {
  int idx = blockIdx.x * 256 + threadIdx.x;         // one float4 per thread
  float4 v = *(const float4*)(x + (size_t)idx * 4);
  ushort4 o;
  o.x = f2bf(v.x); o.y = f2bf(v.y); o.z = f2bf(v.z); o.w = f2bf(v.w);
  *(ushort4*)(xbf + (size_t)idx * 4) = o;
}

// ---------------------------------------------------------------------------
// Weight prep: WT[f][m] = W{q,k,v}[h][m][d] (f = g*512 + h*64 + d), bf16.
//              WoT[m][f] = Wo[f][m], bf16.
// ---------------------------------------------------------------------------
__global__ __launch_bounds__(256) void prep_w_kernel(
    const float* __restrict__ Wq, const float* __restrict__ Wk,
    const float* __restrict__ Wv, const float* __restrict__ Wo,
    ushort* __restrict__ WT, ushort* __restrict__ WoT) {
  int idx = blockIdx.x * 256 + threadIdx.x;
  if (idx < 1536 * 512) {
    int f = idx >> 9, m = idx & 511;
    int g = f >> 9, fl = f & 511, h = fl >> 6, d = fl & 63;
    const float* W = (g == 0) ? Wq : (g == 1) ? Wk : Wv;
    WT[idx] = f2bf(W[((size_t)h * DM + m) * D + d]);
  } else {
    int i2 = idx - 1536 * 512;                      // [0, 512*512)
    int m = i2 >> 9, f = i2 & 511;
    WoT[(size_t)m * 512 + f] = f2bf(Wo[(size_t)f * DM + m]);
  }
}

// ---------------------------------------------------------------------------
// QKV GEMM: C[s][f] = sum_m xbf[s][m] * WT[f][m]   (M=8192, N=1536, K=512)
// ---------------------------------------------------------------------------
__global__ __launch_bounds__(256) void qkv_gemm_kernel(
    const ushort* __restrict__ A, const ushort* __restrict__ Bm,
    ushort* __restrict__ qb, ushort* __restrict__ kb, ushort* __restrict__ vt) {
  __shared__ ushort As[64][72], Bs[64][72];         // +16B pad per row
  const int tid = threadIdx.x;
  const int m0 = blockIdx.x * 64, n0 = blockIdx.y * 64;
  const int w = tid >> 6, l = tid & 63;
  const int r = l & 15, q = l >> 4;
  const int mh = (w >> 1) * 32, nh = (w & 1) * 32;

  f32x4 acc[2][2] = {};
  const int srow = tid >> 2, sco = (tid & 3) * 16;  // staging: 32B per thread

  for (int k0 = 0; k0 < 512; k0 += 64) {
    const ushort* ap = A + (size_t)(m0 + srow) * 512 + k0 + sco;
    const ushort* bp = Bm + (size_t)(n0 + srow) * 512 + k0 + sco;
    uint4 a0 = *(const uint4*)ap;
    uint4 a1 = *(const uint4*)(ap + 8);
    uint4 b0 = *(const uint4*)bp;
    uint4 b1 = *(const uint4*)(bp + 8);
    __syncthreads();
    *(uint4*)&As[srow][sco] = a0;
    *(uint4*)&As[srow][sco + 8] = a1;
    *(uint4*)&Bs[srow][sco] = b0;
    *(uint4*)&Bs[srow][sco + 8] = b1;
    __syncthreads();
    #pragma unroll
    for (int kk = 0; kk < 64; kk += 32) {
      bf16x8 fa0 = *(const bf16x8*)&As[mh + r][kk + q * 8];
      bf16x8 fa1 = *(const bf16x8*)&As[mh + 16 + r][kk + q * 8];
      bf16x8 fb0 = *(const bf16x8*)&Bs[nh + r][kk + q * 8];
      bf16x8 fb1 = *(const bf16x8*)&Bs[nh + 16 + r][kk + q * 8];
      acc[0][0] = mfma16(fa0, fb0, acc[0][0]);
      acc[0][1] = mfma16(fa0, fb1, acc[0][1]);
      acc[1][0] = mfma16(fa1, fb0, acc[1][0]);
      acc[1][1] = mfma16(fa1, fb1, acc[1][1]);
    }
  }

  const int g = n0 >> 9;                            // 0=q 1=k 2=v, block-uniform
  #pragma unroll
  for (int mi = 0; mi < 2; ++mi)
    #pragma unroll
    for (int nj = 0; nj < 2; ++nj)
      #pragma unroll
      for (int i = 0; i < 4; ++i) {
        int row = m0 + mh + mi * 16 + q * 4 + i;    // global s-row
        int col = n0 + nh + nj * 16 + r;            // global f
        int bb = row >> 10, s = row & 1023;
        int fl = col & 511, h = fl >> 6, d = fl & 63;
        ushort val = f2bf(acc[mi][nj][i]);
        if (g == 0)
          qb[(((size_t)bb * H + h) * S + s) * D + d] = val;
        else if (g == 1)
          kb[(((size_t)bb * H + h) * S + s) * D + d] = val;
        else
          vt[(((size_t)bb * H + h) * D + d) * S + s] = val;
      }
}

// ---------------------------------------------------------------------------
// Attention (production = R10's attn_v2, measured 116us vs 134 for 4-wave):
// 8 waves x 512 threads per 16-row tile.
//  - wave w owns k-cols [w*128, w*128+128): sc[8] (32 VGPR)
//  - 24 waves/CU via __launch_bounds__(512,6) -> +50% TLP vs 4-wave
//  - 3-barrier softmax (local max -> LDS -> global max; local sum -> LDS ->
//    global sum). NOTE R11: single-barrier variant + V-prefetch REGRESSED
//    (+27us) -- register budget at (512,6) is ~80 VGPR; extending mxl/corr
//    lifetimes across the barrier + vpre[4] spills. Keep this shape.
//  - tail role-split: waves 0-3 PV, waves 4-7 stream attn full-line nt
//    stores (overlaps store burst with MFMA).
// Clean-instrument facts (R10): FETCH 24.7MB (K/V read once; no locality
// problem, no spill), latency-bound (VALU 23%, MFMA 5%) -> TLP is the lever.
// ---------------------------------------------------------------------------
__global__ __launch_bounds__(512, 6) void attn_kernel(
    const ushort* __restrict__ qb, const ushort* __restrict__ kb,
    const ushort* __restrict__ vt, float* __restrict__ attn,
    ushort* __restrict__ concat) {
  __shared__ ushort Pl[16 * 1024];                  // 32 KB swizzled bf16 P
  __shared__ float redm[8][16], redsum[8][16];      // 1 KB
  __shared__ float rinvL[16];
  const int tid = threadIdx.x;
  const int w = tid >> 6, l = tid & 63;
  const int r = l & 15, q = l >> 4;

  const int n = blockIdx.x;
  const int rank = n >> 3;
  const int bh = (n & 7) * 8 + (rank >> 6);
  const int s0 = (rank & 63) * 16;

  const ushort* qp = qb + ((size_t)bh * S + s0) * D;
  bf16x8 qa0 = *(const bf16x8*)(qp + r * 64 + q * 8);
  bf16x8 qa1 = *(const bf16x8*)(qp + r * 64 + 32 + q * 8);

  // scores: sc[kt][i] = S[q*4+i][w*128 + kt*16 + r] * 1/8   (kt < 8)
  const ushort* kp = kb + (size_t)bh * S * D;
  f32x4 sc[8];
  #pragma unroll
  for (int kt = 0; kt < 8; ++kt) {
    const ushort* kr = kp + (size_t)(w * 128 + kt * 16 + r) * 64 + q * 8;
    bf16x8 kf0 = *(const bf16x8*)kr;
    bf16x8 kf1 = *(const bf16x8*)(kr + 32);
    f32x4 a = {};
    a = mfma16(qa0, kf0, a);
    a = mfma16(qa1, kf1, a);
    sc[kt] = a * 0.125f;
  }

  // row max: lane-local (8), cross-r shuffle, cross-wave (8) via LDS
  float mx[4];
  #pragma unroll
  for (int i = 0; i < 4; ++i) {
    float m = sc[0][i];
    #pragma unroll
    for (int kt = 1; kt < 8; ++kt) m = fmaxf(m, sc[kt][i]);
    #pragma unroll
    for (int msk = 1; msk < 16; msk <<= 1) m = fmaxf(m, __shfl_xor(m, msk));
    mx[i] = m;
  }
  if (r == 0) {
    #pragma unroll
    for (int i = 0; i < 4; ++i) redm[w][q * 4 + i] = mx[i];
  }
  __syncthreads();
  #pragma unroll
  for (int i = 0; i < 4; ++i) {
    int rr = q * 4 + i;
    float m = fmaxf(fmaxf(redm[0][rr], redm[1][rr]),
                    fmaxf(redm[2][rr], redm[3][rr]));
    m = fmaxf(m, fmaxf(fmaxf(redm[4][rr], redm[5][rr]),
                       fmaxf(redm[6][rr], redm[7][rr])));
    mx[i] = m;
  }

  // exp + row sums
  float sm[4] = {0.f, 0.f, 0.f, 0.f};
  #pragma unroll
  for (int kt = 0; kt < 8; ++kt)
    #pragma unroll
    for (int i = 0; i < 4; ++i) {
      float e = __expf(sc[kt][i] - mx[i]);
      sc[kt][i] = e;
      sm[i] += e;
    }
  #pragma unroll
  for (int i = 0; i < 4; ++i) {
    float s = sm[i];
    #pragma unroll
    for (int msk = 1; msk < 16; msk <<= 1) s += __shfl_xor(s, msk);
    sm[i] = s;
  }
  if (r == 0) {
    #pragma unroll
    for (int i = 0; i < 4; ++i) redsum[w][q * 4 + i] = sm[i];
  }
  __syncthreads();
  float rinv[4];
  #pragma unroll
  for (int i = 0; i < 4; ++i) {
    int rr = q * 4 + i;
    float s = (redsum[0][rr] + redsum[1][rr]) + (redsum[2][rr] + redsum[3][rr]) +
              (redsum[4][rr] + redsum[5][rr]) + (redsum[6][rr] + redsum[7][rr]);
    rinv[i] = 1.0f / s;
  }
  if (w == 0 && r == 0) {
    #pragma unroll
    for (int i = 0; i < 4; ++i) rinvL[q * 4 + i] = rinv[i];
  }

  // P -> swizzled LDS (wave w covers cols [w*128, w*128+128))
  #pragma unroll
  for (int kt = 0; kt < 8; ++kt) {
    int col = w * 128 + kt * 16 + r;
    #pragma unroll
    for (int i = 0; i < 4; ++i) {
      int row = q * 4 + i;
      Pl[row * 1024 + (col ^ ((row & 7) << 3))] = f2bf(sc[kt][i]);
    }
  }
  __syncthreads();

  if (w < 4) {
    // PV: wave w owns d-tile [w*16, w*16+16)
    const int d0 = w * 16;
    const ushort* vp = vt + ((size_t)bh * D + d0 + r) * S;
    f32x4 acc[4] = {};
    #pragma unroll
    for (int stp = 0; stp < 32; ++stp) {
      int t0 = stp * 32 + q * 8;
      bf16x8 pa = *(const bf16x8*)&Pl[r * 1024 + (t0 ^ ((r & 7) << 3))];
      bf16x8 vb = *(const bf16x8*)(vp + t0);
      acc[stp & 3] = mfma16(pa, vb, acc[stp & 3]);
    }
    f32x4 tot = acc[0] + acc[1] + acc[2] + acc[3];
    const int b = bh >> 3, h = bh & 7;
    #pragma unroll
    for (int i = 0; i < 4; ++i)
      concat[((size_t)b * S + s0 + q * 4 + i) * DM + h * D + d0 + r] =
          f2bf(tot[i] * rinv[i]);
  } else {
    // attn f32 stores, full-line nt: wave (w-4) streams rows [(w-4)*4, +4)
    const int ws = w - 4;
    float* ap = attn + ((size_t)bh * S + s0) * S;
    #pragma unroll
    for (int uu = 0; uu < 16; ++uu) {
      const int row = ws * 4 + (uu >> 2);
      const int chunk = uu & 3;
      const int c = chunk * 256 + l * 4;
      const int swz = (row & 7) << 3;
      ushort4 p4 = *(const ushort4*)&Pl[row * 1024 + (c ^ swz)];
      const float rv = rinvL[row];
      f32x4 o;
      o.x = bf2f(p4.x) * rv;
      o.y = bf2f(p4.y) * rv;
      o.z = bf2f(p4.z) * rv;
      o.w = bf2f(p4.w) * rv;
      __builtin_nontemporal_store(o, (f32x4*)(ap + (size_t)row * S + c));
    }
  }
}

// ---------------------------------------------------------------------------
// Out-proj GEMM: z[s][m] = sum_f concat[s][f] * WoT[m][f]  (M=8192,N=512,K=512)
// ---------------------------------------------------------------------------
__global__ __launch_bounds__(256) void outproj_gemm_kernel(
    const ushort* __restrict__ A, const ushort* __restrict__ Bm,
    float* __restrict__ z) {
  __shared__ ushort As[64][72], Bs[64][72];
  const int tid = threadIdx.x;
  const int m0 = blockIdx.x * 64, n0 = blockIdx.y * 64;
  const int w = tid >> 6, l = tid & 63;
  const int r = l & 15, q = l >> 4;
  const int mh = (w >> 1) * 32, nh = (w & 1) * 32;

  f32x4 acc[2][2] = {};
  const int srow = tid >> 2, sco = (tid & 3) * 16;

  for (int k0 = 0; k0 < 512; k0 += 64) {
    const ushort* ap = A + (size_t)(m0 + srow) * 512 + k0 + sco;
    const ushort* bp = Bm + (size_t)(n0 + srow) * 512 + k0 + sco;
    uint4 a0 = *(const uint4*)ap;
    uint4 a1 = *(const uint4*)(ap + 8);
    uint4 b0 = *(const uint4*)bp;
    uint4 b1 = *(const uint4*)(bp + 8);
    __syncthreads();
    *(uint4*)&As[srow][sco] = a0;
    *(uint4*)&As[srow][sco + 8] = a1;
    *(uint4*)&Bs[srow][sco] = b0;
    *(uint4*)&Bs[srow][sco + 8] = b1;
    __syncthreads();
    #pragma unroll
    for (int kk = 0; kk < 64; kk += 32) {
      bf16x8 fa0 = *(const bf16x8*)&As[mh + r][kk + q * 8];
      bf16x8 fa1 = *(const bf16x8*)&As[mh + 16 + r][kk + q * 8];
      bf16x8 fb0 = *(const bf16x8*)&Bs[nh + r][kk + q * 8];
      bf16x8 fb1 = *(const bf16x8*)&Bs[nh + 16 + r][kk + q * 8];
      acc[0][0] = mfma16(fa0, fb0, acc[0][0]);
      acc[0][1] = mfma16(fa0, fb1, acc[0][1]);
      acc[1][0] = mfma16(fa1, fb0, acc[1][0]);
      acc[1][1] = mfma16(fa1, fb1, acc[1][1]);
    }
  }

  #pragma unroll
  for (int mi = 0; mi < 2; ++mi)
    #pragma unroll
    for (int nj = 0; nj < 2; ++nj)
      #pragma unroll
      for (int i = 0; i < 4; ++i) {
        int row = m0 + mh + mi * 16 + q * 4 + i;
        int col = n0 + nh + nj * 16 + r;
        z[(size_t)row * DM + col] = acc[mi][nj][i];
      }
}

// ---------------------------------------------------------------------------
extern "C" void kernel_launch(void* const* d_in, const int* in_sizes, int n_in,
                              void* d_out, int out_size, void* d_ws, size_t ws_size,
                              hipStream_t stream) {
  const float* x  = (const float*)d_in[0];
  const float* Wq = (const float*)d_in[1];
  const float* Wk = (const float*)d_in[2];
  const float* Wv = (const float*)d_in[3];
  const float* Wo = (const float*)d_in[4];

  float* z    = (float*)d_out;                      // [B,S,DM]
  float* attn = z + (size_t)B * S * DM;             // [B,H,S,S]

  ushort* xbf    = (ushort*)d_ws;                   // [8192][512]
  ushort* WT     = xbf + (size_t)8192 * 512;        // [1536][512]
  ushort* WoT    = WT + (size_t)1536 * 512;         // [512][512]
  ushort* qb     = WoT + (size_t)512 * 512;         // [B,H,S,D]
  ushort* kb     = qb + (size_t)B * H * S * D;      // [B,H,S,D]
  ushort* vt     = kb + (size_t)B * H * S * D;      // [B,H,D,S]
  ushort* concat = vt + (size_t)B * H * S * D;      // [8192][512]

  cast_x_kernel<<<(B * S * DM / 4 + 255) / 256, 256, 0, stream>>>(x, xbf);
  prep_w_kernel<<<(1536 * 512 + 512 * 512) / 256, 256, 0, stream>>>(
      Wq, Wk, Wv, Wo, WT, WoT);
  qkv_gemm_kernel<<<dim3(8192 / 64, 1536 / 64), 256, 0, stream>>>(
      xbf, WT, qb, kb, vt);
  attn_kernel<<<4096, 512, 0, stream>>>(qb, kb, vt, attn, concat);
  outproj_gemm_kernel<<<dim3(8192 / 64, 512 / 64), 256, 0, stream>>>(
      concat, WoT, z);
}

// Round 13
// 190.839 us; speedup vs baseline: 6.5890x; 1.0187x over previous
//
#include <hip/hip_runtime.h>

#define B 8
#define S 1024
#define DM 512
#define H 8
#define D 64

typedef __attribute__((ext_vector_type(8))) short bf16x8;
typedef __attribute__((ext_vector_type(4))) float f32x4;

__device__ inline f32x4 mfma16(bf16x8 a, bf16x8 b, f32x4 c) {
  return __builtin_amdgcn_mfma_f32_16x16x32_bf16(a, b, c, 0, 0, 0);
}

__device__ inline ushort f2bf(float f) {
  uint u = __float_as_uint(f);
  u += 0x7fff + ((u >> 16) & 1);   // round-to-nearest-even
  return (ushort)(u >> 16);
}

__device__ inline float bf2f(ushort u) {
  return __uint_as_float(((uint)u) << 16);
}

// ---------------------------------------------------------------------------
// Cast x [B,S,DM] f32 -> bf16, vectorized.
// ---------------------------------------------------------------------------
__global__ __launch_bounds__(256) void cast_x_kernel(const float* __restrict__ x,
                                                     ushort* __restrict__ xbf) {
  int idx = blockIdx.x * 256 + threadIdx.x;         // one float4 per thread
  float4 v = *(const float4*)(x + (size_t)idx * 4);
  ushort4 o;
  o.x = f2bf(v.x); o.y = f2bf(v.y); o.z = f2bf(v.z); o.w = f2bf(v.w);
  *(ushort4*)(xbf + (size_t)idx * 4) = o;
}

// ---------------------------------------------------------------------------
// Weight prep: WT[f][m] = W{q,k,v}[h][m][d] (f = g*512 + h*64 + d), bf16.
//              WoT[m][f] = Wo[f][m], bf16.
// ---------------------------------------------------------------------------
__global__ __launch_bounds__(256) void prep_w_kernel(
    const float* __restrict__ Wq, const float* __restrict__ Wk,
    const float* __restrict__ Wv, const float* __restrict__ Wo,
    ushort* __restrict__ WT, ushort* __restrict__ WoT) {
  int idx = blockIdx.x * 256 + threadIdx.x;
  if (idx < 1536 * 512) {
    int f = idx >> 9, m = idx & 511;
    int g = f >> 9, fl = f & 511, h = fl >> 6, d = fl & 63;
    const float* W = (g == 0) ? Wq : (g == 1) ? Wk : Wv;
    WT[idx] = f2bf(W[((size_t)h * DM + m) * D + d]);
  } else {
    int i2 = idx - 1536 * 512;                      // [0, 512*512)
    int m = i2 >> 9, f = i2 & 511;
    WoT[(size_t)m * 512 + f] = f2bf(Wo[(size_t)f * DM + m]);
  }
}

// ---------------------------------------------------------------------------
// QKV GEMM: C[s][f] = sum_m xbf[s][m] * WT[f][m]   (M=8192, N=1536, K=512)
// ---------------------------------------------------------------------------
__global__ __launch_bounds__(256) void qkv_gemm_kernel(
    const ushort* __restrict__ A, const ushort* __restrict__ Bm,
    ushort* __restrict__ qb, ushort* __restrict__ kb, ushort* __restrict__ vt) {
  __shared__ ushort As[64][72], Bs[64][72];         // +16B pad per row
  const int tid = threadIdx.x;
  const int m0 = blockIdx.x * 64, n0 = blockIdx.y * 64;
  const int w = tid >> 6, l = tid & 63;
  const int r = l & 15, q = l >> 4;
  const int mh = (w >> 1) * 32, nh = (w & 1) * 32;

  f32x4 acc[2][2] = {};
  const int srow = tid >> 2, sco = (tid & 3) * 16;  // staging: 32B per thread

  for (int k0 = 0; k0 < 512; k0 += 64) {
    const ushort* ap = A + (size_t)(m0 + srow) * 512 + k0 + sco;
    const ushort* bp = Bm + (size_t)(n0 + srow) * 512 + k0 + sco;
    uint4 a0 = *(const uint4*)ap;
    uint4 a1 = *(const uint4*)(ap + 8);
    uint4 b0 = *(const uint4*)bp;
    uint4 b1 = *(const uint4*)(bp + 8);
    __syncthreads();
    *(uint4*)&As[srow][sco] = a0;
    *(uint4*)&As[srow][sco + 8] = a1;
    *(uint4*)&Bs[srow][sco] = b0;
    *(uint4*)&Bs[srow][sco + 8] = b1;
    __syncthreads();
    #pragma unroll
    for (int kk = 0; kk < 64; kk += 32) {
      bf16x8 fa0 = *(const bf16x8*)&As[mh + r][kk + q * 8];
      bf16x8 fa1 = *(const bf16x8*)&As[mh + 16 + r][kk + q * 8];
      bf16x8 fb0 = *(const bf16x8*)&Bs[nh + r][kk + q * 8];
      bf16x8 fb1 = *(const bf16x8*)&Bs[nh + 16 + r][kk + q * 8];
      acc[0][0] = mfma16(fa0, fb0, acc[0][0]);
      acc[0][1] = mfma16(fa0, fb1, acc[0][1]);
      acc[1][0] = mfma16(fa1, fb0, acc[1][0]);
      acc[1][1] = mfma16(fa1, fb1, acc[1][1]);
    }
  }

  const int g = n0 >> 9;                            // 0=q 1=k 2=v, block-uniform
  #pragma unroll
  for (int mi = 0; mi < 2; ++mi)
    #pragma unroll
    for (int nj = 0; nj < 2; ++nj)
      #pragma unroll
      for (int i = 0; i < 4; ++i) {
        int row = m0 + mh + mi * 16 + q * 4 + i;    // global s-row
        int col = n0 + nh + nj * 16 + r;            // global f
        int bb = row >> 10, s = row & 1023;
        int fl = col & 511, h = fl >> 6, d = fl & 63;
        ushort val = f2bf(acc[mi][nj][i]);
        if (g == 0)
          qb[(((size_t)bb * H + h) * S + s) * D + d] = val;
        else if (g == 1)
          kb[(((size_t)bb * H + h) * S + s) * D + d] = val;
        else
          vt[(((size_t)bb * H + h) * D + d) * S + s] = val;
      }
}

// ---------------------------------------------------------------------------
// Attention: best-measured R8 config (4 waves, 186.6us total) with two
// store-path edits:
//  (1) attn stores are PLAIN f32x4 (nt flag REMOVED -- nt bypasses normal
//      L2 write-combining; the 6.5-7 TB/s harness fills use plain stores;
//      our nt path measured only ~2.1 TB/s effective).
//  (2) store phase moved BEFORE PV: it depends only on Pl+rinvL, so the
//      ~1400 cycles of PV MFMA + V loads now cover the write drain.
// Ledger: T_attn ~134-142us for every prior variant (4w/8w, nt, full-line,
// locality remaps); FETCH 24.7MB = reads once; latency/write-drain-bound.
// ---------------------------------------------------------------------------
__global__ __launch_bounds__(256, 4) void attn_kernel(
    const ushort* __restrict__ qb, const ushort* __restrict__ kb,
    const ushort* __restrict__ vt, float* __restrict__ attn,
    ushort* __restrict__ concat) {
  __shared__ ushort Pl[16 * 1024];                  // 32 KB, swizzled bf16 P
  __shared__ float redm[4][16], redsum[4][16];      // 512 B
  __shared__ float rinvL[16];                       // per-row 1/sum broadcast
  const int tid = threadIdx.x;
  const int w = tid >> 6, l = tid & 63;
  const int r = l & 15, q = l >> 4;

  const int n = blockIdx.x;
  const int rank = n >> 3;
  const int bh = (n & 7) * 8 + (rank >> 6);
  const int s0 = (rank & 63) * 16;

  const ushort* qp = qb + ((size_t)bh * S + s0) * D;
  bf16x8 qa0 = *(const bf16x8*)(qp + r * 64 + q * 8);
  bf16x8 qa1 = *(const bf16x8*)(qp + r * 64 + 32 + q * 8);

  const ushort* kp = kb + (size_t)bh * S * D;
  f32x4 sc[16];
  #pragma unroll
  for (int kt = 0; kt < 16; ++kt) {
    const ushort* kr = kp + (size_t)(w * 256 + kt * 16 + r) * 64 + q * 8;
    bf16x8 kf0 = *(const bf16x8*)kr;
    bf16x8 kf1 = *(const bf16x8*)(kr + 32);
    f32x4 a = {};
    a = mfma16(qa0, kf0, a);
    a = mfma16(qa1, kf1, a);
    sc[kt] = a * 0.125f;
  }

  // row max: lane-local over kt, then across the 16 r-lanes
  float mx[4];
  #pragma unroll
  for (int i = 0; i < 4; ++i) {
    float m = sc[0][i];
    #pragma unroll
    for (int kt = 1; kt < 16; ++kt) m = fmaxf(m, sc[kt][i]);
    #pragma unroll
    for (int msk = 1; msk < 16; msk <<= 1) m = fmaxf(m, __shfl_xor(m, msk));
    mx[i] = m;
  }
  if (r == 0) {
    #pragma unroll
    for (int i = 0; i < 4; ++i) redm[w][q * 4 + i] = mx[i];
  }
  __syncthreads();
  #pragma unroll
  for (int i = 0; i < 4; ++i)
    mx[i] = fmaxf(fmaxf(redm[0][q * 4 + i], redm[1][q * 4 + i]),
                  fmaxf(redm[2][q * 4 + i], redm[3][q * 4 + i]));

  // exp (unnormalized P in regs) + row sums
  float sm[4] = {0.f, 0.f, 0.f, 0.f};
  #pragma unroll
  for (int kt = 0; kt < 16; ++kt)
    #pragma unroll
    for (int i = 0; i < 4; ++i) {
      float e = __expf(sc[kt][i] - mx[i]);
      sc[kt][i] = e;
      sm[i] += e;
    }
  #pragma unroll
  for (int i = 0; i < 4; ++i) {
    float s = sm[i];
    #pragma unroll
    for (int msk = 1; msk < 16; msk <<= 1) s += __shfl_xor(s, msk);
    sm[i] = s;
  }
  if (r == 0) {
    #pragma unroll
    for (int i = 0; i < 4; ++i) redsum[w][q * 4 + i] = sm[i];
  }
  __syncthreads();
  float rinv[4];
  #pragma unroll
  for (int i = 0; i < 4; ++i)
    rinv[i] = 1.0f / (redsum[0][q * 4 + i] + redsum[1][q * 4 + i] +
                      redsum[2][q * 4 + i] + redsum[3][q * 4 + i]);
  if (w == 0 && r == 0) {
    #pragma unroll
    for (int i = 0; i < 4; ++i) rinvL[q * 4 + i] = rinv[i];
  }

  // write P bf16 (unnormalized) to swizzled LDS
  #pragma unroll
  for (int kt = 0; kt < 16; ++kt) {
    int col = w * 256 + kt * 16 + r;
    #pragma unroll
    for (int i = 0; i < 4; ++i) {
      int row = q * 4 + i;
      Pl[row * 1024 + (col ^ ((row & 7) << 3))] = f2bf(sc[kt][i]);
    }
  }
  __syncthreads();

  // attn f32 store FIRST (full-line, PLAIN stores): wave w streams rows
  // [w*4, w*4+4), 4 chunks of 256 cols per row; per instruction all 64
  // lanes write one row (lane li -> cols 4*li) = 1 KB contiguous.
  // Fire-and-forget: PV below covers the drain.
  {
    float* ap = attn + ((size_t)bh * S + s0) * S;
    #pragma unroll
    for (int uu = 0; uu < 16; ++uu) {
      const int row = w * 4 + (uu >> 2);
      const int chunk = uu & 3;
      const int c = chunk * 256 + l * 4;
      const int swz = (row & 7) << 3;
      ushort4 p4 = *(const ushort4*)&Pl[row * 1024 + (c ^ swz)];
      const float rv = rinvL[row];
      f32x4 o;
      o.x = bf2f(p4.x) * rv;
      o.y = bf2f(p4.y) * rv;
      o.z = bf2f(p4.z) * rv;
      o.w = bf2f(p4.w) * rv;
      *(f32x4*)(ap + (size_t)row * S + c) = o;
    }
  }

  // PV: wave w owns d-tile [w*16, w*16+16); A = P (LDS), B = V^T (global/L2)
  {
    const int d0 = w * 16;
    const ushort* vp = vt + ((size_t)bh * D + d0 + r) * S;
    f32x4 acc[4] = {};
    #pragma unroll
    for (int stp = 0; stp < 32; ++stp) {
      int t0 = stp * 32 + q * 8;
      bf16x8 pa = *(const bf16x8*)&Pl[r * 1024 + (t0 ^ ((r & 7) << 3))];
      bf16x8 vb = *(const bf16x8*)(vp + t0);
      acc[stp & 3] = mfma16(pa, vb, acc[stp & 3]);
    }
    f32x4 tot = acc[0] + acc[1] + acc[2] + acc[3];
    const int b = bh >> 3, h = bh & 7;
    #pragma unroll
    for (int i = 0; i < 4; ++i)
      concat[((size_t)b * S + s0 + q * 4 + i) * DM + h * D + d0 + r] =
          f2bf(tot[i] * rinv[i]);
  }
}

// ---------------------------------------------------------------------------
// Out-proj GEMM: z[s][m] = sum_f concat[s][f] * WoT[m][f]  (M=8192,N=512,K=512)
// ---------------------------------------------------------------------------
__global__ __launch_bounds__(256) void outproj_gemm_kernel(
    const ushort* __restrict__ A, const ushort* __restrict__ Bm,
    float* __restrict__ z) {
  __shared__ ushort As[64][72], Bs[64][72];
  const int tid = threadIdx.x;
  const int m0 = blockIdx.x * 64, n0 = blockIdx.y * 64;
  const int w = tid >> 6, l = tid & 63;
  const int r = l & 15, q = l >> 4;
  const int mh = (w >> 1) * 32, nh = (w & 1) * 32;

  f32x4 acc[2][2] = {};
  const int srow = tid >> 2, sco = (tid & 3) * 16;

  for (int k0 = 0; k0 < 512; k0 += 64) {
    const ushort* ap = A + (size_t)(m0 + srow) * 512 + k0 + sco;
    const ushort* bp = Bm + (size_t)(n0 + srow) * 512 + k0 + sco;
    uint4 a0 = *(const uint4*)ap;
    uint4 a1 = *(const uint4*)(ap + 8);
    uint4 b0 = *(const uint4*)bp;
    uint4 b1 = *(const uint4*)(bp + 8);
    __syncthreads();
    *(uint4*)&As[srow][sco] = a0;
    *(uint4*)&As[srow][sco + 8] = a1;
    *(uint4*)&Bs[srow][sco] = b0;
    *(uint4*)&Bs[srow][sco + 8] = b1;
    __syncthreads();
    #pragma unroll
    for (int kk = 0; kk < 64; kk += 32) {
      bf16x8 fa0 = *(const bf16x8*)&As[mh + r][kk + q * 8];
      bf16x8 fa1 = *(const bf16x8*)&As[mh + 16 + r][kk + q * 8];
      bf16x8 fb0 = *(const bf16x8*)&Bs[nh + r][kk + q * 8];
      bf16x8 fb1 = *(const bf16x8*)&Bs[nh + 16 + r][kk + q * 8];
      acc[0][0] = mfma16(fa0, fb0, acc[0][0]);
      acc[0][1] = mfma16(fa0, fb1, acc[0][1]);
      acc[1][0] = mfma16(fa1, fb0, acc[1][0]);
      acc[1][1] = mfma16(fa1, fb1, acc[1][1]);
    }
  }

  #pragma unroll
  for (int mi = 0; mi < 2; ++mi)
    #pragma unroll
    for (int nj = 0; nj < 2; ++nj)
      #pragma unroll
      for (int i = 0; i < 4; ++i) {
        int row = m0 + mh + mi * 16 + q * 4 + i;
        int col = n0 + nh + nj * 16 + r;
        z[(size_t)row * DM + col] = acc[mi][nj][i];
      }
}

// ---------------------------------------------------------------------------
extern "C" void kernel_launch(void* const* d_in, const int* in_sizes, int n_in,
                              void* d_out, int out_size, void* d_ws, size_t ws_size,
                              hipStream_t stream) {
  const float* x  = (const float*)d_in[0];
  const float* Wq = (const float*)d_in[1];
  const float* Wk = (const float*)d_in[2];
  const float* Wv = (const float*)d_in[3];
  const float* Wo = (const float*)d_in[4];

  float* z    = (float*)d_out;                      // [B,S,DM]
  float* attn = z + (size_t)B * S * DM;             // [B,H,S,S]

  ushort* xbf    = (ushort*)d_ws;                   // [8192][512]
  ushort* WT     = xbf + (size_t)8192 * 512;        // [1536][512]
  ushort* WoT    = WT + (size_t)1536 * 512;         // [512][512]
  ushort* qb     = WoT + (size_t)512 * 512;         // [B,H,S,D]
  ushort* kb     = qb + (size_t)B * H * S * D;      // [B,H,S,D]
  ushort* vt     = kb + (size_t)B * H * S * D;      // [B,H,D,S]
  ushort* concat = vt + (size_t)B * H * S * D;      // [8192][512]

  cast_x_kernel<<<(B * S * DM / 4 + 255) / 256, 256, 0, stream>>>(x, xbf);
  prep_w_kernel<<<(1536 * 512 + 512 * 512) / 256, 256, 0, stream>>>(
      Wq, Wk, Wv, Wo, WT, WoT);
  qkv_gemm_kernel<<<dim3(8192 / 64, 1536 / 64), 256, 0, stream>>>(
      xbf, WT, qb, kb, vt);
  attn_kernel<<<4096, 256, 0, stream>>>(qb, kb, vt, attn, concat);
  outproj_gemm_kernel<<<dim3(8192 / 64, 512 / 64), 256, 0, stream>>>(
      concat, WoT, z);
}